// Round 1
// baseline (656.932 us; speedup 1.0000x reference)
//
#include <hip/hip_runtime.h>
#include <math.h>

// Problem constants (B=2, T=512 -> N=1024 tokens)
constexpr int N    = 1024;
constexpr int DIM  = 512;
constexpr int HID  = 2048;
constexpr int NE   = 64;

__device__ inline void fma4(float4& a, float s, const float4& w) {
    a.x = fmaf(s, w.x, a.x);
    a.y = fmaf(s, w.y, a.y);
    a.z = fmaf(s, w.z, a.z);
    a.w = fmaf(s, w.w, a.w);
}

// ---------------------------------------------------------------------------
// Gating: logits = (x @ emb^T)/sqrt(din); softmax; gate=max prob; idx=argmax.
// f64 accumulation so argmax matches the true argmax. 4 tokens per block
// (amortizes emb re-reads 4x). 256 threads: 4 threads per expert.
// ---------------------------------------------------------------------------
template <int DIN>
__global__ __launch_bounds__(256) void gating_kernel(
    const float* __restrict__ X, const float* __restrict__ emb,
    float* __restrict__ gate, int* __restrict__ idx, int* __restrict__ cnt)
{
    constexpr int TPB = 4;
    const int n0  = blockIdx.x * TPB;
    const int tid = threadIdx.x;

    __shared__ float  xs[TPB][DIN];
    __shared__ double red[256];

    for (int i = tid; i < TPB * (DIN / 4); i += 256) {
        const int tk = i / (DIN / 4), j = i % (DIN / 4);
        ((float4*)xs[tk])[j] = ((const float4*)(X + (size_t)(n0 + tk) * DIN))[j];
    }
    __syncthreads();

    const int e    = tid >> 2;
    const int part = tid & 3;
    constexpr int SEG = DIN / 4;

    const float4* w4 = (const float4*)(emb + (size_t)e * DIN + part * SEG);
    double acc[TPB] = {0.0, 0.0, 0.0, 0.0};

    for (int i = 0; i < SEG / 4; i++) {
        const float4 wv = w4[i];
        #pragma unroll
        for (int tk = 0; tk < TPB; tk++) {
            const float4 xv = ((const float4*)(xs[tk] + part * SEG))[i];
            acc[tk] += (double)xv.x * (double)wv.x + (double)xv.y * (double)wv.y
                     + (double)xv.z * (double)wv.z + (double)xv.w * (double)wv.w;
        }
    }

    for (int tk = 0; tk < TPB; tk++) {
        red[tid] = acc[tk];
        __syncthreads();
        if (tid < 64) {  // wave 0
            double s = red[tid * 4] + red[tid * 4 + 1] + red[tid * 4 + 2] + red[tid * 4 + 3];
            float  l = (float)(s / sqrt((double)DIN));

            float m = l; int mi = tid;
            #pragma unroll
            for (int off = 32; off > 0; off >>= 1) {
                float om = __shfl_down(m, off);
                int   oi = __shfl_down(mi, off);
                if (om > m || (om == m && oi < mi)) { m = om; mi = oi; }
            }
            m  = __shfl(m, 0);
            mi = __shfl(mi, 0);

            float p = expf(l - m);
            float ss = p;
            #pragma unroll
            for (int off = 32; off > 0; off >>= 1) ss += __shfl_down(ss, off);

            if (tid == 0) {
                gate[n0 + tk] = 1.0f / ss;
                idx[n0 + tk]  = mi;
                atomicAdd(&cnt[mi], 1);
            }
        }
        __syncthreads();
    }
}

// ---------------------------------------------------------------------------
// Fused exclusive-scan + ranked scatter. One block, N threads (N=1024).
// Replaces the old scan_kernel + scatter_kernel pair (saves one launch).
// ---------------------------------------------------------------------------
__global__ __launch_bounds__(1024) void scan_scatter(
    const int* __restrict__ cnt, const int* __restrict__ idx,
    int* __restrict__ off, int* __restrict__ bucket)
{
    __shared__ int soff[NE];
    __shared__ int scur[NE];
    const int tid = threadIdx.x;

    if (tid == 0) {
        int s = 0;
        for (int e = 0; e < NE; e++) { soff[e] = s; off[e] = s; s += cnt[e]; }
    }
    if (tid < NE) scur[tid] = 0;
    __syncthreads();

    const int e = idx[tid];
    const int p = atomicAdd(&scur[e], 1);
    bucket[soff[e] + p] = tid;
}

// ---------------------------------------------------------------------------
// Grouped GEMM layer 1 + gate scale + exact GELU.
// grid = (NE, HID/256) = (64, 8) -> 512 blocks -> 2 blocks/CU (2 waves/SIMD),
// vs. the previous 256-block layout that pinned us at 1 wave/SIMD and could
// not hide HBM latency. W1 [E][DIM][HID] still streamed exactly once.
// Block: 4 token-groups (8 tokens each) x 64 col-threads (4 cols each).
// W loads explicitly software-pipelined one dg-group ahead.
// ---------------------------------------------------------------------------
__global__ __launch_bounds__(256, 2) void moe_gemm1(
    const float* __restrict__ X,  const float* __restrict__ W1,
    const float* __restrict__ b1, const float* __restrict__ gate,
    const int* __restrict__ cnt,  const int* __restrict__ off,
    const int* __restrict__ bucket, float* __restrict__ H)
{
    const int e    = blockIdx.x;
    const int mt   = cnt[e];
    if (mt == 0) return;
    const int base = off[e];
    const int tid  = threadIdx.x;
    const int tg   = tid >> 6;                       // token group (8 tokens)
    const int c    = blockIdx.y * 256 + (tid & 63) * 4;

    __shared__ float xs[32][DIM];                    // 64 KB -> 2 blocks/CU

    const float* Wc = W1 + (size_t)e * DIM * HID + c;
    const float4 bias4 = *(const float4*)(b1 + (size_t)e * HID + c);

    for (int chunk = 0; chunk < mt; chunk += 32) {
        const int m = min(32, mt - chunk);

        for (int i = tid; i < m * (DIM / 4); i += 256) {
            const int t = i >> 7, j = i & 127;
            ((float4*)xs[t])[j] =
                ((const float4*)(X + (size_t)bucket[base + chunk + t] * DIM))[j];
        }
        __syncthreads();

        float4 acc[8];
        #pragma unroll
        for (int t = 0; t < 8; t++) acc[t] = make_float4(0.f, 0.f, 0.f, 0.f);

        // software pipeline: wr holds dg's 4 W rows, wn prefetches dg+1's
        float4 wr[4];
        #pragma unroll
        for (int r = 0; r < 4; r++)
            wr[r] = *(const float4*)(Wc + (size_t)r * HID);

        for (int dg = 0; dg < DIM / 4; dg++) {
            float4 wn[4];
            const bool more = (dg + 1 < DIM / 4);
            if (more) {
                const float* wq = Wc + (size_t)(dg + 1) * 4 * HID;
                #pragma unroll
                for (int r = 0; r < 4; r++)
                    wn[r] = *(const float4*)(wq + (size_t)r * HID);
            }
            #pragma unroll
            for (int t = 0; t < 8; t++) {
                const float4 xv = *(const float4*)&xs[tg * 8 + t][dg * 4];
                fma4(acc[t], xv.x, wr[0]);
                fma4(acc[t], xv.y, wr[1]);
                fma4(acc[t], xv.z, wr[2]);
                fma4(acc[t], xv.w, wr[3]);
            }
            if (more) {
                #pragma unroll
                for (int r = 0; r < 4; r++) wr[r] = wn[r];
            }
        }

        #pragma unroll
        for (int t = 0; t < 8; t++) {
            const int ti = chunk + tg * 8 + t;
            if (ti < mt) {
                const int   tok = bucket[base + ti];
                const float g   = gate[tok];
                float4 v;
                v.x = g * (acc[t].x + bias4.x);
                v.y = g * (acc[t].y + bias4.y);
                v.z = g * (acc[t].z + bias4.z);
                v.w = g * (acc[t].w + bias4.w);
                v.x = 0.5f * v.x * (1.0f + erff(v.x * 0.70710678118654752f));
                v.y = 0.5f * v.y * (1.0f + erff(v.y * 0.70710678118654752f));
                v.z = 0.5f * v.z * (1.0f + erff(v.z * 0.70710678118654752f));
                v.w = 0.5f * v.w * (1.0f + erff(v.w * 0.70710678118654752f));
                *(float4*)(H + (size_t)tok * HID + c) = v;
            }
        }
        __syncthreads();
    }
}

// ---------------------------------------------------------------------------
// Grouped GEMM layer 2 + gate scale. grid = (NE, DIM/256, 4 K-slices)
// = (64, 2, 4) -> 512 blocks -> 2 blocks/CU. W2 [E][HID][DIM] streamed once.
// K-split partials combined via atomicAdd into zeroed out.
// ---------------------------------------------------------------------------
__global__ __launch_bounds__(256, 2) void moe_gemm2(
    const float* __restrict__ Hm, const float* __restrict__ W2,
    const float* __restrict__ b2, const float* __restrict__ gate,
    const int* __restrict__ cnt,  const int* __restrict__ off,
    const int* __restrict__ bucket, float* __restrict__ out)
{
    const int e    = blockIdx.x;
    const int z    = blockIdx.z;                     // K-slice, 512 rows each
    const int mt   = cnt[e];
    if (mt == 0) return;
    const int base = off[e];
    const int tid  = threadIdx.x;
    const int tg   = tid >> 6;                       // token group (8 tokens)
    const int c    = blockIdx.y * 256 + (tid & 63) * 4;

    __shared__ float xs[32][512];                    // 64 KB (K-slice of H rows)

    const float* Wc = W2 + (size_t)e * HID * DIM + (size_t)z * 512 * DIM + c;
    float4 bias4 = make_float4(0.f, 0.f, 0.f, 0.f);
    if (z == 0) bias4 = *(const float4*)(b2 + (size_t)e * DIM + c);

    for (int chunk = 0; chunk < mt; chunk += 32) {
        const int m = min(32, mt - chunk);

        for (int i = tid; i < m * 128; i += 256) {
            const int t = i >> 7, j = i & 127;
            ((float4*)xs[t])[j] =
                ((const float4*)(Hm + (size_t)bucket[base + chunk + t] * HID + z * 512))[j];
        }
        __syncthreads();

        float4 acc[8];
        #pragma unroll
        for (int t = 0; t < 8; t++) acc[t] = make_float4(0.f, 0.f, 0.f, 0.f);

        float4 wr[4];
        #pragma unroll
        for (int r = 0; r < 4; r++)
            wr[r] = *(const float4*)(Wc + (size_t)r * DIM);

        for (int dg = 0; dg < 128; dg++) {
            float4 wn[4];
            const bool more = (dg + 1 < 128);
            if (more) {
                const float* wq = Wc + (size_t)(dg + 1) * 4 * DIM;
                #pragma unroll
                for (int r = 0; r < 4; r++)
                    wn[r] = *(const float4*)(wq + (size_t)r * DIM);
            }
            #pragma unroll
            for (int t = 0; t < 8; t++) {
                const float4 xv = *(const float4*)&xs[tg * 8 + t][dg * 4];
                fma4(acc[t], xv.x, wr[0]);
                fma4(acc[t], xv.y, wr[1]);
                fma4(acc[t], xv.z, wr[2]);
                fma4(acc[t], xv.w, wr[3]);
            }
            if (more) {
                #pragma unroll
                for (int r = 0; r < 4; r++) wr[r] = wn[r];
            }
        }

        #pragma unroll
        for (int t = 0; t < 8; t++) {
            const int ti = chunk + tg * 8 + t;
            if (ti < mt) {
                const int   tok = bucket[base + ti];
                const float g   = gate[tok];
                float* o = out + (size_t)tok * DIM + c;
                atomicAdd(o + 0, g * (acc[t].x + bias4.x));
                atomicAdd(o + 1, g * (acc[t].y + bias4.y));
                atomicAdd(o + 2, g * (acc[t].z + bias4.z));
                atomicAdd(o + 3, g * (acc[t].w + bias4.w));
            }
        }
        __syncthreads();
    }
}

// ---------------------------------------------------------------------------
extern "C" void kernel_launch(void* const* d_in, const int* in_sizes, int n_in,
                              void* d_out, int out_size, void* d_ws, size_t ws_size,
                              hipStream_t stream)
{
    const float* x    = (const float*)d_in[0];
    const float* emb1 = (const float*)d_in[1];
    const float* W1   = (const float*)d_in[2];
    const float* b1   = (const float*)d_in[3];
    const float* emb2 = (const float*)d_in[4];
    const float* W2   = (const float*)d_in[5];
    const float* b2   = (const float*)d_in[6];
    float* out = (float*)d_out;

    // workspace layout (~8.03 MB)
    float* H       = (float*)d_ws;              // N*HID
    float* gate1   = H + (size_t)N * HID;       // N
    float* gate2   = gate1 + N;                 // N
    int*   idx1    = (int*)(gate2 + N);         // N
    int*   idx2    = idx1 + N;                  // N
    int*   bucket1 = idx2 + N;                  // N
    int*   bucket2 = bucket1 + N;               // N
    int*   cnt1    = bucket2 + N;               // 4*NE contiguous ints below
    int*   off1    = cnt1 + NE;
    int*   cnt2    = off1 + NE;
    int*   off2    = cnt2 + NE;

    hipMemsetAsync(cnt1, 0, 4 * NE * sizeof(int), stream);
    hipMemsetAsync(out, 0, (size_t)N * DIM * sizeof(float), stream);

    // layer 1
    gating_kernel<DIM><<<N / 4, 256, 0, stream>>>(x, emb1, gate1, idx1, cnt1);
    scan_scatter<<<1, N, 0, stream>>>(cnt1, idx1, off1, bucket1);
    moe_gemm1<<<dim3(NE, HID / 256), 256, 0, stream>>>(x, W1, b1, gate1, cnt1, off1,
                                                       bucket1, H);
    // layer 2
    gating_kernel<HID><<<N / 4, 256, 0, stream>>>(H, emb2, gate2, idx2, cnt2);
    scan_scatter<<<1, N, 0, stream>>>(cnt2, idx2, off2, bucket2);
    moe_gemm2<<<dim3(NE, DIM / 256, 4), 256, 0, stream>>>(H, W2, b2, gate2, cnt2, off2,
                                                          bucket2, out);
}